// Round 5
// baseline (556.666 us; speedup 1.0000x reference)
//
#include <hip/hip_runtime.h>

// RVQ: z [16,64,4096] f32, codebooks [8,1024,64] f32 -> zq + 8 losses + 8 perplexities
#define S      8
#define K      1024
#define D      64
#define NVEC   65536
#define NBLK   1024      // 4-wave blocks, 64 vectors each
#define NW     4096      // loss partials (one per wave)
#define NELEM  4194304.0f
#define EPSQ   1e-10f
#define DELTA  0.005f    // exact-rescan margin >> split-bf16 score error (~2e-3 worst)

typedef __attribute__((ext_vector_type(8))) short  short8;   // 8 bf16
typedef __attribute__((ext_vector_type(4))) float  float4v;  // MFMA acc

static __device__ inline unsigned short f2bf(float f) {
    unsigned int u = __float_as_uint(f);
    u = (u + 0x7FFFu + ((u >> 16) & 1u)) >> 16;
    return (unsigned short)u;
}
static __device__ inline float bf2f(unsigned short h) {
    return __uint_as_float(((unsigned int)h) << 16);
}

// async global->LDS, 16 B per lane. LDS dest is WAVE-UNIFORM base (HW adds
// lane*16); global src is per-lane (m104 semantics).
static __device__ inline void gll16(const void* g, void* l) {
    __builtin_amdgcn_global_load_lds(
        (const __attribute__((address_space(1))) unsigned int*)g,
        (__attribute__((address_space(3))) unsigned int*)l,
        16, 0, 0);
}

// ---------------------------------------------------------------------------
// Prep: (a) c2 + zero cnt; (b) interleave codebook into B-fragment streaming
// records, PRE-SCALED BY -2 so the MFMA accumulates -2*dot directly and the
// accumulator is seeded with c2 (score = acc, no per-score fmaf).
// Record = 4KB per (stage, 16-cw tile): 4 segments [h0h][h1h][h0l][h1l],
// each segment = 64 lanes x 16B contiguous.
// ---------------------------------------------------------------------------
__global__ void rvq_prep(const float* __restrict__ cb,
                         unsigned short* __restrict__ cbi,
                         float* __restrict__ c2, unsigned* __restrict__ cnt) {
    int i = blockIdx.x * blockDim.x + threadIdx.x;   // 0..32767
    if (i < S * K) {   // c2 + cnt zero
        const float* row = cb + (size_t)i * D;
        float a0 = 0.f, a1 = 0.f, a2 = 0.f, a3 = 0.f;
#pragma unroll
        for (int d = 0; d < D; d += 4) {
            a0 = fmaf(row[d+0], row[d+0], a0);
            a1 = fmaf(row[d+1], row[d+1], a1);
            a2 = fmaf(row[d+2], row[d+2], a2);
            a3 = fmaf(row[d+3], row[d+3], a3);
        }
        c2[i] = (a0 + a1) + (a2 + a3);
        cnt[i] = 0u;
    }
    // interleave: i = s*4096 + tau*64 + l
    int s  = i >> 12;
    int tau = (i >> 6) & 63;
    int l  = i & 63;
    int m  = l & 15, qq = l >> 4;
    const float* row = cb + (size_t)(s * K + tau * 16 + m) * D;
    short8 h0h, h0l, h1h, h1l;
#pragma unroll
    for (int e = 0; e < 8; ++e) {
        float x = -2.0f * row[qq * 8 + e];
        unsigned short h = f2bf(x);
        h0h[e] = (short)h; h0l[e] = (short)f2bf(x - bf2f(h));
        float y = -2.0f * row[32 + qq * 8 + e];
        unsigned short g = f2bf(y);
        h1h[e] = (short)g; h1l[e] = (short)f2bf(y - bf2f(g));
    }
    unsigned short* rec = cbi + (size_t)(s * 64 + tau) * 2048 + l * 8;
    *(short8*)(rec +    0) = h0h;
    *(short8*)(rec +  512) = h1h;
    *(short8*)(rec + 1024) = h0l;
    *(short8*)(rec + 1536) = h1l;
}

// ---------------------------------------------------------------------------
// Main (R5): 1024 blocks x 4 waves, 64 vectors/block, wave w owns rows
// [w*16, w*16+16) -- NO duplicated tail work (R2 lesson). Each 4KB codebook
// tile is staged ONCE per block into LDS (global_load_lds, wave w stages
// segment w -> 1 VMEM/wave/tile, 4x fewer codebook loads than R4, which was
// the invariant across the flat R0/R2/R4 results). Double-buffered 2-tile
// phases, counted vmcnt(2) (NEVER drained in-loop; raw s_barrier, not
// __syncthreads which emits vmcnt(0)). c2 staged to LDS per stage so no
// stray VMEM disturbs the vmcnt counting (stray tail VMEMs are OLDER than
// counted loads; vmcnt retires in issue order -> counting stays correct).
//
// launch_bounds EMPIRICAL RULE (R0-R4, 4 data points on this toolchain):
// VGPR cap = 256/arg2 regardless of block size. arg2 MUST stay 2
// (cap 128 >= ~95 needed). (x,4) capped at 64 -> catastrophic spill twice.
// ---------------------------------------------------------------------------
__global__ __launch_bounds__(256, 2)
void rvq_main(const float* __restrict__ z, const float* __restrict__ cbf,
              const unsigned short* __restrict__ cbi,
              const float* __restrict__ c2, float* __restrict__ zq,
              float* __restrict__ lossp, unsigned* __restrict__ cnt) {
    const int tid  = threadIdx.x;
    const int lane = tid & 63;
    const int w    = tid >> 6;              // wave id 0..3
    const int m    = lane & 15;
    const int q    = lane >> 4;
    const int bid  = blockIdx.x;
    const int vbase = bid * 64;             // 64 vectors per block
    const int b    = vbase >> 12;
    const int ta   = (vbase & 4095) + w * 16 + m;   // this wave's row t
    const size_t zrow = ((size_t)(b * 64)) << 12;

    __shared__ unsigned short lds_t[2][2][2048];    // [buf][tile][4KB]
    __shared__ float c2l[K];                        // stage's c2, 4KB

    float ra0[8], ra1[8];
#pragma unroll
    for (int i = 0; i < 8; ++i) {
        ra0[i] = z[zrow + ((size_t)(q*8+i)    << 12) + ta];
        ra1[i] = z[zrow + ((size_t)(32+q*8+i) << 12) + ta];
    }

#pragma unroll 1
    for (int s = 0; s < S; ++s) {
        // split residuals to bf16 hi/lo A-fragments
        short8 xa0h, xa0l, xa1h, xa1l;
#pragma unroll
        for (int i = 0; i < 8; ++i) {
            unsigned short h;
            h = f2bf(ra0[i]); xa0h[i] = (short)h; xa0l[i] = (short)f2bf(ra0[i] - bf2f(h));
            h = f2bf(ra1[i]); xa1h[i] = (short)h; xa1l[i] = (short)f2bf(ra1[i] - bf2f(h));
        }

        float b1a[4], b2a[4];
        int   k1a[4];
#pragma unroll
        for (int j = 0; j < 4; ++j) {
            b1a[j] = 3.4e38f; b2a[j] = 3.4e38f; k1a[j] = 0;
        }

        const unsigned short* recs = cbi + (size_t)s * 131072;
        const float*          c2s  = c2 + s * K;

        // ---- prologue: issue c2 (1 VMEM) + phases 0,1 (2 VMEM each) ----
        gll16(c2s + w * 256 + lane * 4, &c2l[w * 256]);
#pragma unroll
        for (int t_ = 0; t_ < 2; ++t_)
            gll16(recs + (size_t)t_ * 2048 + w * 512 + lane * 8,
                  &lds_t[0][t_][w * 512]);
#pragma unroll
        for (int t_ = 0; t_ < 2; ++t_)
            gll16(recs + (size_t)(2 + t_) * 2048 + w * 512 + lane * 8,
                  &lds_t[1][t_][w * 512]);

        // ---- 32 phases x 2 tiles, double-buffered, counted vmcnt ----
#pragma unroll 1
        for (int p = 0; p < 32; ++p) {
            if (p == 31) { asm volatile("s_waitcnt vmcnt(0)" ::: "memory"); }
            else         { asm volatile("s_waitcnt vmcnt(2)" ::: "memory"); }
            __builtin_amdgcn_s_barrier();           // phase p published
            asm volatile("" ::: "memory");
            const int bf = p & 1;
#pragma unroll
            for (int t_ = 0; t_ < 2; ++t_) {
                const int tt = p * 2 + t_;
                const unsigned short* base = &lds_t[bf][t_][lane * 8];
                short8 bh0 = *(const short8*)(base);
                short8 bh1 = *(const short8*)(base + 512);
                short8 bl0 = *(const short8*)(base + 1024);
                short8 bl1 = *(const short8*)(base + 1536);
                float  c2v = c2l[tt * 16 + m];
                float4v aa = {c2v, c2v, c2v, c2v};
                __builtin_amdgcn_s_setprio(1);
                aa = __builtin_amdgcn_mfma_f32_16x16x32_bf16(xa0h, bh0, aa, 0,0,0);
                aa = __builtin_amdgcn_mfma_f32_16x16x32_bf16(xa0l, bh0, aa, 0,0,0);
                aa = __builtin_amdgcn_mfma_f32_16x16x32_bf16(xa0h, bl0, aa, 0,0,0);
                aa = __builtin_amdgcn_mfma_f32_16x16x32_bf16(xa1h, bh1, aa, 0,0,0);
                aa = __builtin_amdgcn_mfma_f32_16x16x32_bf16(xa1l, bh1, aa, 0,0,0);
                aa = __builtin_amdgcn_mfma_f32_16x16x32_bf16(xa1h, bl1, aa, 0,0,0);
                __builtin_amdgcn_s_setprio(0);
                const int ncol = tt * 16 + m;
#pragma unroll
                for (int j = 0; j < 4; ++j) {
                    float sa = aa[j];
                    // second-best = median of {s, b1, b2}
                    b2a[j] = __builtin_amdgcn_fmed3f(sa, b1a[j], b2a[j]);
                    k1a[j] = (sa < b1a[j]) ? ncol : k1a[j];
                    b1a[j] = fminf(sa, b1a[j]);
                }
            }
            asm volatile("" ::: "memory");
            __builtin_amdgcn_s_barrier();           // buf[bf] fully consumed
            if (p < 30) {                           // stage phase p+2 into bf
#pragma unroll
                for (int t_ = 0; t_ < 2; ++t_) {
                    const int tt = (p + 2) * 2 + t_;
                    gll16(recs + (size_t)tt * 2048 + w * 512 + lane * 8,
                          &lds_t[bf][t_][w * 512]);
                }
            }
        }

        // ---- reduce across the 16 col-lanes (k-tie: lowest k) ----
#pragma unroll
        for (int off = 1; off < 16; off <<= 1) {
#pragma unroll
            for (int j = 0; j < 4; ++j) {
                float o1 = __shfl_xor(b1a[j], off); int ok = __shfl_xor(k1a[j], off);
                float o2 = __shfl_xor(b2a[j], off);
                float n2 = fminf(fminf(b2a[j], o2), fmaxf(b1a[j], o1));
                bool tk = (o1 < b1a[j]) || (o1 == b1a[j] && ok < k1a[j]);
                k1a[j] = tk ? ok : k1a[j]; b1a[j] = fminf(b1a[j], o1); b2a[j] = n2;
            }
        }

        // ---- δ-rescue: exact fp32 rescan of ambiguous rows (rare) ----
        const float* cr0 = cbf + (size_t)s * 65536;
#define RESCUE(b1X, b2X, k1X, R0, R1)                                         \
        for (int j = 0; j < 4; ++j) {                                         \
            unsigned long long mask = __ballot(b2X[j] - b1X[j] < DELTA);      \
            while (mask) {                                                    \
                int lq = (int)(__builtin_ctzll(mask)) >> 4;                   \
                mask &= ~(0xFFFFULL << (lq * 16));                            \
                int mrow = lq * 4 + j;                                        \
                float bd = 3.4e38f; int bk = 0;                               \
                for (int cc = 0; cc < 16; ++cc) {                             \
                    int n = cc * 64 + lane;                                   \
                    const float* crow = cr0 + (size_t)n * 64;                 \
                    float dot = 0.f;                                          \
                    for (int p2 = 0; p2 < 4; ++p2) {                          \
                        for (int i = 0; i < 8; ++i)                           \
                            dot = fmaf(__shfl(R0[i], mrow + 16*p2), crow[p2*8+i], dot); \
                        for (int i = 0; i < 8; ++i)                           \
                            dot = fmaf(__shfl(R1[i], mrow + 16*p2), crow[32+p2*8+i], dot); \
                    }                                                         \
                    float sc = c2s[n] - 2.f * dot;                            \
                    if (sc < bd) { bd = sc; bk = n; }                         \
                }                                                             \
                for (int off = 1; off < 64; off <<= 1) {                      \
                    float ob = __shfl_xor(bd, off); int ok = __shfl_xor(bk, off); \
                    bool tk = (ob < bd) || (ob == bd && ok < bk);             \
                    bk = tk ? ok : bk; bd = fminf(bd, ob);                    \
                }                                                             \
                if (q == lq) k1X[j] = bk;                                     \
            }                                                                 \
        }
        RESCUE(b1a, b2a, k1a, ra0, ra1)
#undef RESCUE

        // ---- transpose winners to per-lane rows (row = m), convergent ----
        int mm = m & 3, src = (m >> 2) * 16;
        int wa0 = __shfl(k1a[0], src), wa1 = __shfl(k1a[1], src);
        int wa2 = __shfl(k1a[2], src), wa3 = __shfl(k1a[3], src);
        int bka = (mm == 0) ? wa0 : (mm == 1) ? wa1 : (mm == 2) ? wa2 : wa3;

        // ---- fp32 residual update ----
        const float* qa = cbf + (size_t)s * 65536 + (size_t)bka * 64;
#pragma unroll
        for (int i = 0; i < 8; ++i) {
            ra0[i] -= qa[q*8+i];  ra1[i] -= qa[32+q*8+i];
        }

        // ---- loss: per-wave partial store ----
        float ls = 0.f;
#pragma unroll
        for (int i = 0; i < 8; ++i) {
            ls = fmaf(ra0[i], ra0[i], ls); ls = fmaf(ra1[i], ra1[i], ls);
        }
#pragma unroll
        for (int off = 1; off < 64; off <<= 1) ls += __shfl_xor(ls, off);
        if (lane == 0) lossp[s * NW + bid * 4 + w] = ls;

        // ---- histogram: bka is per-vector winner (dup across q) ----
        if (q == 0) atomicAdd(&cnt[s * K + bka], 1u);
    }

    // ---- epilogue: zq = z - r_final ----
#pragma unroll
    for (int i = 0; i < 8; ++i) {
        size_t a0 = zrow + ((size_t)(q*8+i)    << 12) + ta;
        size_t a1 = zrow + ((size_t)(32+q*8+i) << 12) + ta;
        zq[a0] = z[a0] - ra0[i];
        zq[a1] = z[a1] - ra1[i];
    }
}

// ---------------------------------------------------------------------------
// Finalize: losses (mean of summed wave partials) + perplexities
// ---------------------------------------------------------------------------
__global__ void rvq_finalize(const float* __restrict__ lossp,
                             const unsigned* __restrict__ cnt,
                             float* __restrict__ out_loss,
                             float* __restrict__ out_perp) {
    const int s   = blockIdx.x;
    const int tid = threadIdx.x;
    float ent = 0.f, lsum = 0.f;
    for (int i = tid; i < K; i += 256) {
        float p = (float)cnt[s * K + i] * (1.0f / 65536.0f);
        ent += p * logf(p + EPSQ);
    }
    for (int i = tid; i < NW; i += 256) lsum += lossp[s * NW + i];
    __shared__ float redE[4], redL[4];
#pragma unroll
    for (int off = 32; off > 0; off >>= 1) {
        ent  += __shfl_down(ent, off);
        lsum += __shfl_down(lsum, off);
    }
    if ((tid & 63) == 0) { redE[tid >> 6] = ent; redL[tid >> 6] = lsum; }
    __syncthreads();
    if (tid == 0) {
        float te = redE[0] + redE[1] + redE[2] + redE[3];
        float tl = redL[0] + redL[1] + redL[2] + redL[3];
        out_perp[s] = expf(-te);
        out_loss[s] = tl * (1.0f / NELEM);
    }
}

// ---------------------------------------------------------------------------
extern "C" void kernel_launch(void* const* d_in, const int* in_sizes, int n_in,
                              void* d_out, int out_size, void* d_ws, size_t ws_size,
                              hipStream_t stream) {
    const float* z  = (const float*)d_in[0];
    const float* cb = (const float*)d_in[1];

    float* zq       = (float*)d_out;
    float* out_loss = zq + 4194304;
    float* out_perp = out_loss + 8;

    // ws: cbi 2 MB | c2 32 KB | cnt 32 KB | lossp 128 KB
    char* ws = (char*)d_ws;
    unsigned short* cbi = (unsigned short*)(ws);
    float*    c2    = (float*)(ws + 2097152);
    unsigned* cnt   = (unsigned*)(ws + 2129920);
    float*    lossp = (float*)(ws + 2162688);

    hipLaunchKernelGGL(rvq_prep,     dim3(128),  dim3(256), 0, stream, cb, cbi, c2, cnt);
    hipLaunchKernelGGL(rvq_main,     dim3(NBLK), dim3(256), 0, stream, z, cb, cbi, c2, zq, lossp, cnt);
    hipLaunchKernelGGL(rvq_finalize, dim3(S),    dim3(256), 0, stream, lossp, cnt, out_loss, out_perp);
}

// Round 6
// 431.598 us; speedup vs baseline: 1.2898x; 1.2898x over previous
//
#include <hip/hip_runtime.h>

// RVQ: z [16,64,4096] f32, codebooks [8,1024,64] f32 -> zq + 8 losses + 8 perplexities
#define S      8
#define K      1024
#define D      64
#define NVEC   65536
#define NW     4096      // single-wave blocks, 16 vectors each
#define NELEM  4194304.0f
#define EPSQ   1e-10f
#define DELTA  0.005f    // exact-rescan margin >> split-bf16 score error (~2e-3 worst)

typedef __attribute__((ext_vector_type(8))) short  short8;   // 8 bf16
typedef __attribute__((ext_vector_type(4))) float  float4v;  // MFMA acc

static __device__ inline unsigned short f2bf(float f) {
    unsigned int u = __float_as_uint(f);
    u = (u + 0x7FFFu + ((u >> 16) & 1u)) >> 16;
    return (unsigned short)u;
}
static __device__ inline float bf2f(unsigned short h) {
    return __uint_as_float(((unsigned int)h) << 16);
}

// ---------------------------------------------------------------------------
// Prep: (a) c2 + zero cnt; (b) interleave codebook into B-fragment streaming
// records, PRE-SCALED BY -2 so the MFMA accumulates -2*dot directly and the
// accumulator is seeded with c2 (score = acc, no per-score fmaf).
// Record = 4KB per (stage, 16-cw tile): segments at byte 0/1024/2048/3072
// ([h0h][h1h][h0l][h1l]), each segment 64 lanes x 16B -> imm-offset friendly.
// ---------------------------------------------------------------------------
__global__ void rvq_prep(const float* __restrict__ cb,
                         unsigned short* __restrict__ cbi,
                         float* __restrict__ c2, unsigned* __restrict__ cnt) {
    int i = blockIdx.x * blockDim.x + threadIdx.x;   // 0..32767
    if (i < S * K) {   // c2 + cnt zero
        const float* row = cb + (size_t)i * D;
        float a0 = 0.f, a1 = 0.f, a2 = 0.f, a3 = 0.f;
#pragma unroll
        for (int d = 0; d < D; d += 4) {
            a0 = fmaf(row[d+0], row[d+0], a0);
            a1 = fmaf(row[d+1], row[d+1], a1);
            a2 = fmaf(row[d+2], row[d+2], a2);
            a3 = fmaf(row[d+3], row[d+3], a3);
        }
        c2[i] = (a0 + a1) + (a2 + a3);
        cnt[i] = 0u;
    }
    // interleave: i = s*4096 + tau*64 + l
    int s  = i >> 12;
    int tau = (i >> 6) & 63;
    int l  = i & 63;
    int m  = l & 15, qq = l >> 4;
    const float* row = cb + (size_t)(s * K + tau * 16 + m) * D;
    short8 h0h, h0l, h1h, h1l;
#pragma unroll
    for (int e = 0; e < 8; ++e) {
        float x = -2.0f * row[qq * 8 + e];
        unsigned short h = f2bf(x);
        h0h[e] = (short)h; h0l[e] = (short)f2bf(x - bf2f(h));
        float y = -2.0f * row[32 + qq * 8 + e];
        unsigned short g = f2bf(y);
        h1h[e] = (short)g; h1l[e] = (short)f2bf(y - bf2f(g));
    }
    unsigned short* rec = cbi + (size_t)(s * 64 + tau) * 2048 + l * 8;
    *(short8*)(rec +    0) = h0h;
    *(short8*)(rec +  512) = h1h;
    *(short8*)(rec + 1024) = h0l;
    *(short8*)(rec + 1536) = h1l;
}

// ---------------------------------------------------------------------------
// Main (R6): 4096 independent single-wave blocks, 16 vectors each (best
// structure, R4) with the VALU-overhead diet. R5 post-mortem: R0/R2/R4 all
// ~443-455us regardless of wave count / codebook traffic -> binder is
// per-tile VALU overhead (64-bit per-lane address math for 5 loads/tile +
// 16 v_mov bank copies/tile), not VMEM BW. Fixes here:
//  1) uniform loop-carried SCALAR base pointers (tp += 4096 / cp += 64,
//     SALU) + one fixed per-lane VGPR offset; segment selects via imm
//     offset 0/1024/2048/3072 -> saddr-form loads, ~0 VALU per tile.
//  2) 4 named banks, tau unrolled x4, reload AFTER consume -> register
//     reuse without copies, ~4-tile prefetch distance kept.
//  3) split accumulators: two independent 3-MFMA chains (halved dep
//     latency), add at score time.
//
// launch_bounds EMPIRICAL RULE (R0-R4): VGPR cap = 256/arg2 on this
// toolchain. arg2 MUST stay 2 (cap 128). (x,4) capped at 64 -> spill, twice.
// ---------------------------------------------------------------------------
__global__ __launch_bounds__(64, 2)
void rvq_main(const float* __restrict__ z, const float* __restrict__ cbf,
              const unsigned short* __restrict__ cbi,
              const float* __restrict__ c2, float* __restrict__ zq,
              float* __restrict__ lossp, unsigned* __restrict__ cnt) {
    const int lane = threadIdx.x;
    const int m    = lane & 15;
    const int q    = lane >> 4;
    const int wid  = blockIdx.x;
    const int vbase = wid * 16;
    const int b    = vbase >> 12;
    const int ta   = (vbase & 4095) + m;
    const size_t zrow = ((size_t)(b * 64)) << 12;
    const int lo16 = lane * 16;     // per-lane byte offset into a segment
    const int lom  = m * 4;         // per-lane byte offset into c2 tile

    float ra0[8], ra1[8];
#pragma unroll
    for (int i = 0; i < 8; ++i) {
        ra0[i] = z[zrow + ((size_t)(q*8+i)    << 12) + ta];
        ra1[i] = z[zrow + ((size_t)(32+q*8+i) << 12) + ta];
    }

// load one 4KB tile record + its c2 scalar; advance uniform bases (SALU)
#define LOADB(i) {                                                           \
        B##i##0 = *(const short8*)(tp + lo16);                               \
        B##i##1 = *(const short8*)(tp + lo16 + 1024);                        \
        B##i##2 = *(const short8*)(tp + lo16 + 2048);                        \
        B##i##3 = *(const short8*)(tp + lo16 + 3072);                        \
        cc##i   = *(const float*)(cp + lom);                                 \
        tp += 4096; cp += 64;                                                \
    }

// two independent 3-MFMA chains (dims 0-31 seeded c2, dims 32-63 seeded 0)
#define COMPUTE(i, tt) {                                                     \
        float4v a0 = {cc##i, cc##i, cc##i, cc##i};                           \
        float4v a1 = {0.f, 0.f, 0.f, 0.f};                                   \
        __builtin_amdgcn_s_setprio(1);                                       \
        a0 = __builtin_amdgcn_mfma_f32_16x16x32_bf16(xa0h, B##i##0, a0, 0,0,0); \
        a1 = __builtin_amdgcn_mfma_f32_16x16x32_bf16(xa1h, B##i##1, a1, 0,0,0); \
        a0 = __builtin_amdgcn_mfma_f32_16x16x32_bf16(xa0l, B##i##0, a0, 0,0,0); \
        a1 = __builtin_amdgcn_mfma_f32_16x16x32_bf16(xa1l, B##i##1, a1, 0,0,0); \
        a0 = __builtin_amdgcn_mfma_f32_16x16x32_bf16(xa0h, B##i##2, a0, 0,0,0); \
        a1 = __builtin_amdgcn_mfma_f32_16x16x32_bf16(xa1h, B##i##3, a1, 0,0,0); \
        __builtin_amdgcn_s_setprio(0);                                       \
        const int ncol = (tt) * 16 + m;                                      \
        _Pragma("unroll")                                                    \
        for (int j = 0; j < 4; ++j) {                                        \
            float sa = a0[j] + a1[j];                                        \
            b2a[j] = __builtin_amdgcn_fmed3f(sa, b1a[j], b2a[j]);            \
            k1a[j] = (sa < b1a[j]) ? ncol : k1a[j];                          \
            b1a[j] = fminf(sa, b1a[j]);                                      \
        }                                                                    \
    }

#pragma unroll 1
    for (int s = 0; s < S; ++s) {
        // split residuals to bf16 hi/lo A-fragments
        short8 xa0h, xa0l, xa1h, xa1l;
#pragma unroll
        for (int i = 0; i < 8; ++i) {
            unsigned short h;
            h = f2bf(ra0[i]); xa0h[i] = (short)h; xa0l[i] = (short)f2bf(ra0[i] - bf2f(h));
            h = f2bf(ra1[i]); xa1h[i] = (short)h; xa1l[i] = (short)f2bf(ra1[i] - bf2f(h));
        }

        float b1a[4], b2a[4];
        int   k1a[4];
#pragma unroll
        for (int j = 0; j < 4; ++j) {
            b1a[j] = 3.4e38f; b2a[j] = 3.4e38f; k1a[j] = 0;
        }

        const float* c2s = c2 + s * K;
        const char*  tp  = (const char*)(cbi + (size_t)s * 131072); // uniform
        const char*  cp  = (const char*)c2s;                        // uniform

        short8 B00, B01, B02, B03, B10, B11, B12, B13;
        short8 B20, B21, B22, B23, B30, B31, B32, B33;
        float  cc0, cc1, cc2, cc3;

        // prologue: banks 0..3 <- tiles 0..3
        LOADB(0) LOADB(1) LOADB(2) LOADB(3)

#pragma unroll 1
        for (int it = 0; it < 15; ++it) {
            const int tau = it * 4;
            COMPUTE(0, tau + 0) LOADB(0)     // reload tile tau+4
            COMPUTE(1, tau + 1) LOADB(1)
            COMPUTE(2, tau + 2) LOADB(2)
            COMPUTE(3, tau + 3) LOADB(3)
        }
        COMPUTE(0, 60) COMPUTE(1, 61) COMPUTE(2, 62) COMPUTE(3, 63)

        // ---- reduce across the 16 col-lanes (k-tie: lowest k) ----
#pragma unroll
        for (int off = 1; off < 16; off <<= 1) {
#pragma unroll
            for (int j = 0; j < 4; ++j) {
                float o1 = __shfl_xor(b1a[j], off); int ok = __shfl_xor(k1a[j], off);
                float o2 = __shfl_xor(b2a[j], off);
                float n2 = fminf(fminf(b2a[j], o2), fmaxf(b1a[j], o1));
                bool tk = (o1 < b1a[j]) || (o1 == b1a[j] && ok < k1a[j]);
                k1a[j] = tk ? ok : k1a[j]; b1a[j] = fminf(b1a[j], o1); b2a[j] = n2;
            }
        }

        // ---- δ-rescue: exact fp32 rescan of ambiguous rows (rare) ----
        const float* cr0 = cbf + (size_t)s * 65536;
#define RESCUE(b1X, b2X, k1X, R0, R1)                                         \
        for (int j = 0; j < 4; ++j) {                                         \
            unsigned long long mask = __ballot(b2X[j] - b1X[j] < DELTA);      \
            while (mask) {                                                    \
                int lq = (int)(__builtin_ctzll(mask)) >> 4;                   \
                mask &= ~(0xFFFFULL << (lq * 16));                            \
                int mrow = lq * 4 + j;                                        \
                float bd = 3.4e38f; int bk = 0;                               \
                for (int cc = 0; cc < 16; ++cc) {                             \
                    int n = cc * 64 + lane;                                   \
                    const float* crow = cr0 + (size_t)n * 64;                 \
                    float dot = 0.f;                                          \
                    for (int p2 = 0; p2 < 4; ++p2) {                          \
                        for (int i = 0; i < 8; ++i)                           \
                            dot = fmaf(__shfl(R0[i], mrow + 16*p2), crow[p2*8+i], dot); \
                        for (int i = 0; i < 8; ++i)                           \
                            dot = fmaf(__shfl(R1[i], mrow + 16*p2), crow[32+p2*8+i], dot); \
                    }                                                         \
                    float sc = c2s[n] - 2.f * dot;                            \
                    if (sc < bd) { bd = sc; bk = n; }                         \
                }                                                             \
                for (int off = 1; off < 64; off <<= 1) {                      \
                    float ob = __shfl_xor(bd, off); int ok = __shfl_xor(bk, off); \
                    bool tk = (ob < bd) || (ob == bd && ok < bk);             \
                    bk = tk ? ok : bk; bd = fminf(bd, ob);                    \
                }                                                             \
                if (q == lq) k1X[j] = bk;                                     \
            }                                                                 \
        }
        RESCUE(b1a, b2a, k1a, ra0, ra1)
#undef RESCUE

        // ---- transpose winners to per-lane rows (row = m), convergent ----
        int mm = m & 3, src = (m >> 2) * 16;
        int wa0 = __shfl(k1a[0], src), wa1 = __shfl(k1a[1], src);
        int wa2 = __shfl(k1a[2], src), wa3 = __shfl(k1a[3], src);
        int bka = (mm == 0) ? wa0 : (mm == 1) ? wa1 : (mm == 2) ? wa2 : wa3;

        // ---- fp32 residual update ----
        const float* qa = cbf + (size_t)s * 65536 + (size_t)bka * 64;
#pragma unroll
        for (int i = 0; i < 8; ++i) {
            ra0[i] -= qa[q*8+i];  ra1[i] -= qa[32+q*8+i];
        }

        // ---- loss: plain per-wave store (summed in finalize) ----
        float ls = 0.f;
#pragma unroll
        for (int i = 0; i < 8; ++i) {
            ls = fmaf(ra0[i], ra0[i], ls); ls = fmaf(ra1[i], ra1[i], ls);
        }
#pragma unroll
        for (int off = 1; off < 64; off <<= 1) ls += __shfl_xor(ls, off);
        if (lane == 0) lossp[s * NW + wid] = ls;

        // ---- histogram: bka is per-vector winner (dup across q) ----
        if (q == 0) atomicAdd(&cnt[s * K + bka], 1u);
    }
#undef LOADB
#undef COMPUTE

    // ---- epilogue: zq = z - r_final ----
#pragma unroll
    for (int i = 0; i < 8; ++i) {
        size_t a0 = zrow + ((size_t)(q*8+i)    << 12) + ta;
        size_t a1 = zrow + ((size_t)(32+q*8+i) << 12) + ta;
        zq[a0] = z[a0] - ra0[i];
        zq[a1] = z[a1] - ra1[i];
    }
}

// ---------------------------------------------------------------------------
// Finalize: losses (mean of summed wave partials) + perplexities
// ---------------------------------------------------------------------------
__global__ void rvq_finalize(const float* __restrict__ lossp,
                             const unsigned* __restrict__ cnt,
                             float* __restrict__ out_loss,
                             float* __restrict__ out_perp) {
    const int s   = blockIdx.x;
    const int tid = threadIdx.x;
    float ent = 0.f, lsum = 0.f;
    for (int i = tid; i < K; i += 256) {
        float p = (float)cnt[s * K + i] * (1.0f / 65536.0f);
        ent += p * logf(p + EPSQ);
    }
    for (int i = tid; i < NW; i += 256) lsum += lossp[s * NW + i];
    __shared__ float redE[4], redL[4];
#pragma unroll
    for (int off = 32; off > 0; off >>= 1) {
        ent  += __shfl_down(ent, off);
        lsum += __shfl_down(lsum, off);
    }
    if ((tid & 63) == 0) { redE[tid >> 6] = ent; redL[tid >> 6] = lsum; }
    __syncthreads();
    if (tid == 0) {
        float te = redE[0] + redE[1] + redE[2] + redE[3];
        float tl = redL[0] + redL[1] + redL[2] + redL[3];
        out_perp[s] = expf(-te);
        out_loss[s] = tl * (1.0f / NELEM);
    }
}

// ---------------------------------------------------------------------------
extern "C" void kernel_launch(void* const* d_in, const int* in_sizes, int n_in,
                              void* d_out, int out_size, void* d_ws, size_t ws_size,
                              hipStream_t stream) {
    const float* z  = (const float*)d_in[0];
    const float* cb = (const float*)d_in[1];

    float* zq       = (float*)d_out;
    float* out_loss = zq + 4194304;
    float* out_perp = out_loss + 8;

    // ws: cbi 2 MB | c2 32 KB | cnt 32 KB | lossp 128 KB
    char* ws = (char*)d_ws;
    unsigned short* cbi = (unsigned short*)(ws);
    float*    c2    = (float*)(ws + 2097152);
    unsigned* cnt   = (unsigned*)(ws + 2129920);
    float*    lossp = (float*)(ws + 2162688);

    hipLaunchKernelGGL(rvq_prep,     dim3(128),  dim3(256), 0, stream, cb, cbi, c2, cnt);
    hipLaunchKernelGGL(rvq_main,     dim3(NW),   dim3(64),  0, stream, z, cb, cbi, c2, zq, lossp, cnt);
    hipLaunchKernelGGL(rvq_finalize, dim3(S),    dim3(256), 0, stream, lossp, cnt, out_loss, out_perp);
}

// Round 7
// 429.067 us; speedup vs baseline: 1.2974x; 1.0059x over previous
//
#include <hip/hip_runtime.h>

// RVQ: z [16,64,4096] f32, codebooks [8,1024,64] f32 -> zq + 8 losses + 8 perplexities
#define S      8
#define K      1024
#define D      64
#define NVEC   65536
#define NW     4096      // single-wave blocks, 16 vectors each
#define NELEM  4194304.0f
#define EPSQ   1e-10f
#define DELTA  0.005f    // exact-rescan margin >> split-bf16 score error (~2e-3 worst)

typedef __attribute__((ext_vector_type(8))) short  short8;   // 8 bf16
typedef __attribute__((ext_vector_type(4))) float  float4v;  // MFMA acc

static __device__ inline unsigned short f2bf(float f) {
    unsigned int u = __float_as_uint(f);
    u = (u + 0x7FFFu + ((u >> 16) & 1u)) >> 16;
    return (unsigned short)u;
}
static __device__ inline float bf2f(unsigned short h) {
    return __uint_as_float(((unsigned int)h) << 16);
}

// ---------------------------------------------------------------------------
// Prep: (a) c2 + zero cnt; (b) interleave codebook into B-fragment streaming
// records, PRE-SCALED BY -2 so the MFMA accumulates -2*dot directly and the
// accumulator is seeded with c2 (score = acc, no per-score fmaf).
// Record = 4KB per (stage, 16-cw tile): segments at byte 0/1024/2048/3072
// ([h0h][h1h][h0l][h1l]), each segment 64 lanes x 16B -> imm-offset friendly.
// ---------------------------------------------------------------------------
__global__ void rvq_prep(const float* __restrict__ cb,
                         unsigned short* __restrict__ cbi,
                         float* __restrict__ c2, unsigned* __restrict__ cnt) {
    int i = blockIdx.x * blockDim.x + threadIdx.x;   // 0..32767
    if (i < S * K) {   // c2 + cnt zero
        const float* row = cb + (size_t)i * D;
        float a0 = 0.f, a1 = 0.f, a2 = 0.f, a3 = 0.f;
#pragma unroll
        for (int d = 0; d < D; d += 4) {
            a0 = fmaf(row[d+0], row[d+0], a0);
            a1 = fmaf(row[d+1], row[d+1], a1);
            a2 = fmaf(row[d+2], row[d+2], a2);
            a3 = fmaf(row[d+3], row[d+3], a3);
        }
        c2[i] = (a0 + a1) + (a2 + a3);
        cnt[i] = 0u;
    }
    // interleave: i = s*4096 + tau*64 + l
    int s  = i >> 12;
    int tau = (i >> 6) & 63;
    int l  = i & 63;
    int m  = l & 15, qq = l >> 4;
    const float* row = cb + (size_t)(s * K + tau * 16 + m) * D;
    short8 h0h, h0l, h1h, h1l;
#pragma unroll
    for (int e = 0; e < 8; ++e) {
        float x = -2.0f * row[qq * 8 + e];
        unsigned short h = f2bf(x);
        h0h[e] = (short)h; h0l[e] = (short)f2bf(x - bf2f(h));
        float y = -2.0f * row[32 + qq * 8 + e];
        unsigned short g = f2bf(y);
        h1h[e] = (short)g; h1l[e] = (short)f2bf(y - bf2f(g));
    }
    unsigned short* rec = cbi + (size_t)(s * 64 + tau) * 2048 + l * 8;
    *(short8*)(rec +    0) = h0h;
    *(short8*)(rec +  512) = h1h;
    *(short8*)(rec + 1024) = h0l;
    *(short8*)(rec + 1536) = h1l;
}

// ---------------------------------------------------------------------------
// Main (R7): register-footprint cut. R6 post-mortem: across R0/R2/R4/R6 the
// effective residency was stuck at ~2 waves/SIMD whenever arch VGPR was
// 124-128 (occupancy 15-20%), because the unified-RF allocation (VGPR +
// AGPR accumulators, coarse granule) lands above 128/wave -> every round
// ran the SAME effective machine config -> identical ~430us, latency-bound.
// Fix: 2 prefetch banks (-32 VGPR) + single 6-MFMA accumulator chain
// (-4 VGPR, -4 VALU/tile) -> arch VGPR ~100, total incl AGPR <= 128 ->
// 4 waves/SIMD. Grid supplies exactly 16 waves/CU.
//
// launch_bounds EMPIRICAL RULE (R0-R4): VGPR cap = 256/arg2 on this
// toolchain. arg2 MUST stay 2 (cap 128). (x,4) capped at 64 -> spill, twice.
// ---------------------------------------------------------------------------
__global__ __launch_bounds__(64, 2)
void rvq_main(const float* __restrict__ z, const float* __restrict__ cbf,
              const unsigned short* __restrict__ cbi,
              const float* __restrict__ c2, float* __restrict__ zq,
              float* __restrict__ lossp, unsigned* __restrict__ cnt) {
    const int lane = threadIdx.x;
    const int m    = lane & 15;
    const int q    = lane >> 4;
    const int wid  = blockIdx.x;
    const int vbase = wid * 16;
    const int b    = vbase >> 12;
    const int ta   = (vbase & 4095) + m;
    const size_t zrow = ((size_t)(b * 64)) << 12;
    const int lo16 = lane * 16;     // per-lane byte offset into a segment
    const int lom  = m * 4;         // per-lane byte offset into c2 tile

    float ra0[8], ra1[8];
#pragma unroll
    for (int i = 0; i < 8; ++i) {
        ra0[i] = z[zrow + ((size_t)(q*8+i)    << 12) + ta];
        ra1[i] = z[zrow + ((size_t)(32+q*8+i) << 12) + ta];
    }

// load one 4KB tile record + its c2 scalar; advance uniform bases (SALU)
#define LOADB(i) {                                                           \
        B##i##0 = *(const short8*)(tp + lo16);                               \
        B##i##1 = *(const short8*)(tp + lo16 + 1024);                        \
        B##i##2 = *(const short8*)(tp + lo16 + 2048);                        \
        B##i##3 = *(const short8*)(tp + lo16 + 3072);                        \
        cc##i   = *(const float*)(cp + lom);                                 \
        tp += 4096; cp += 64;                                                \
    }

// single 6-MFMA chain seeded c2 (score = acc, dims split hi/lo)
#define COMPUTE(i, tt) {                                                     \
        float4v a0 = {cc##i, cc##i, cc##i, cc##i};                           \
        __builtin_amdgcn_s_setprio(1);                                       \
        a0 = __builtin_amdgcn_mfma_f32_16x16x32_bf16(xa0h, B##i##0, a0, 0,0,0); \
        a0 = __builtin_amdgcn_mfma_f32_16x16x32_bf16(xa0l, B##i##0, a0, 0,0,0); \
        a0 = __builtin_amdgcn_mfma_f32_16x16x32_bf16(xa0h, B##i##2, a0, 0,0,0); \
        a0 = __builtin_amdgcn_mfma_f32_16x16x32_bf16(xa1h, B##i##1, a0, 0,0,0); \
        a0 = __builtin_amdgcn_mfma_f32_16x16x32_bf16(xa1l, B##i##1, a0, 0,0,0); \
        a0 = __builtin_amdgcn_mfma_f32_16x16x32_bf16(xa1h, B##i##3, a0, 0,0,0); \
        __builtin_amdgcn_s_setprio(0);                                       \
        const int ncol = (tt) * 16 + m;                                      \
        _Pragma("unroll")                                                    \
        for (int j = 0; j < 4; ++j) {                                        \
            float sa = a0[j];                                                \
            b2a[j] = __builtin_amdgcn_fmed3f(sa, b1a[j], b2a[j]);            \
            k1a[j] = (sa < b1a[j]) ? ncol : k1a[j];                          \
            b1a[j] = fminf(sa, b1a[j]);                                      \
        }                                                                    \
    }

#pragma unroll 1
    for (int s = 0; s < S; ++s) {
        // split residuals to bf16 hi/lo A-fragments
        short8 xa0h, xa0l, xa1h, xa1l;
#pragma unroll
        for (int i = 0; i < 8; ++i) {
            unsigned short h;
            h = f2bf(ra0[i]); xa0h[i] = (short)h; xa0l[i] = (short)f2bf(ra0[i] - bf2f(h));
            h = f2bf(ra1[i]); xa1h[i] = (short)h; xa1l[i] = (short)f2bf(ra1[i] - bf2f(h));
        }

        float b1a[4], b2a[4];
        int   k1a[4];
#pragma unroll
        for (int j = 0; j < 4; ++j) {
            b1a[j] = 3.4e38f; b2a[j] = 3.4e38f; k1a[j] = 0;
        }

        const float* c2s = c2 + s * K;
        const char*  tp  = (const char*)(cbi + (size_t)s * 131072); // uniform
        const char*  cp  = (const char*)c2s;                        // uniform

        short8 B00, B01, B02, B03, B10, B11, B12, B13;  // two banks
        float  cc0, cc1;

        // prologue: banks 0,1 <- tiles 0,1
        LOADB(0) LOADB(1)

#pragma unroll 1
        for (int it = 0; it < 31; ++it) {
            const int tau = it * 2;
            COMPUTE(0, tau + 0) LOADB(0)     // reload tile tau+2
            COMPUTE(1, tau + 1) LOADB(1)     // reload tile tau+3
        }
        COMPUTE(0, 62) COMPUTE(1, 63)

        // ---- reduce across the 16 col-lanes (k-tie: lowest k) ----
#pragma unroll
        for (int off = 1; off < 16; off <<= 1) {
#pragma unroll
            for (int j = 0; j < 4; ++j) {
                float o1 = __shfl_xor(b1a[j], off); int ok = __shfl_xor(k1a[j], off);
                float o2 = __shfl_xor(b2a[j], off);
                float n2 = fminf(fminf(b2a[j], o2), fmaxf(b1a[j], o1));
                bool tk = (o1 < b1a[j]) || (o1 == b1a[j] && ok < k1a[j]);
                k1a[j] = tk ? ok : k1a[j]; b1a[j] = fminf(b1a[j], o1); b2a[j] = n2;
            }
        }

        // ---- δ-rescue: exact fp32 rescan of ambiguous rows (rare) ----
        const float* cr0 = cbf + (size_t)s * 65536;
#define RESCUE(b1X, b2X, k1X, R0, R1)                                         \
        for (int j = 0; j < 4; ++j) {                                         \
            unsigned long long mask = __ballot(b2X[j] - b1X[j] < DELTA);      \
            while (mask) {                                                    \
                int lq = (int)(__builtin_ctzll(mask)) >> 4;                   \
                mask &= ~(0xFFFFULL << (lq * 16));                            \
                int mrow = lq * 4 + j;                                        \
                float bd = 3.4e38f; int bk = 0;                               \
                for (int cc = 0; cc < 16; ++cc) {                             \
                    int n = cc * 64 + lane;                                   \
                    const float* crow = cr0 + (size_t)n * 64;                 \
                    float dot = 0.f;                                          \
                    for (int p2 = 0; p2 < 4; ++p2) {                          \
                        for (int i = 0; i < 8; ++i)                           \
                            dot = fmaf(__shfl(R0[i], mrow + 16*p2), crow[p2*8+i], dot); \
                        for (int i = 0; i < 8; ++i)                           \
                            dot = fmaf(__shfl(R1[i], mrow + 16*p2), crow[32+p2*8+i], dot); \
                    }                                                         \
                    float sc = c2s[n] - 2.f * dot;                            \
                    if (sc < bd) { bd = sc; bk = n; }                         \
                }                                                             \
                for (int off = 1; off < 64; off <<= 1) {                      \
                    float ob = __shfl_xor(bd, off); int ok = __shfl_xor(bk, off); \
                    bool tk = (ob < bd) || (ob == bd && ok < bk);             \
                    bk = tk ? ok : bk; bd = fminf(bd, ob);                    \
                }                                                             \
                if (q == lq) k1X[j] = bk;                                     \
            }                                                                 \
        }
        RESCUE(b1a, b2a, k1a, ra0, ra1)
#undef RESCUE

        // ---- transpose winners to per-lane rows (row = m), convergent ----
        int mm = m & 3, src = (m >> 2) * 16;
        int wa0 = __shfl(k1a[0], src), wa1 = __shfl(k1a[1], src);
        int wa2 = __shfl(k1a[2], src), wa3 = __shfl(k1a[3], src);
        int bka = (mm == 0) ? wa0 : (mm == 1) ? wa1 : (mm == 2) ? wa2 : wa3;

        // ---- fp32 residual update ----
        const float* qa = cbf + (size_t)s * 65536 + (size_t)bka * 64;
#pragma unroll
        for (int i = 0; i < 8; ++i) {
            ra0[i] -= qa[q*8+i];  ra1[i] -= qa[32+q*8+i];
        }

        // ---- loss: plain per-wave store (summed in finalize) ----
        float ls = 0.f;
#pragma unroll
        for (int i = 0; i < 8; ++i) {
            ls = fmaf(ra0[i], ra0[i], ls); ls = fmaf(ra1[i], ra1[i], ls);
        }
#pragma unroll
        for (int off = 1; off < 64; off <<= 1) ls += __shfl_xor(ls, off);
        if (lane == 0) lossp[s * NW + wid] = ls;

        // ---- histogram: bka is per-vector winner (dup across q) ----
        if (q == 0) atomicAdd(&cnt[s * K + bka], 1u);
    }
#undef LOADB
#undef COMPUTE

    // ---- epilogue: zq = z - r_final ----
#pragma unroll
    for (int i = 0; i < 8; ++i) {
        size_t a0 = zrow + ((size_t)(q*8+i)    << 12) + ta;
        size_t a1 = zrow + ((size_t)(32+q*8+i) << 12) + ta;
        zq[a0] = z[a0] - ra0[i];
        zq[a1] = z[a1] - ra1[i];
    }
}

// ---------------------------------------------------------------------------
// Finalize: losses (mean of summed wave partials) + perplexities
// ---------------------------------------------------------------------------
__global__ void rvq_finalize(const float* __restrict__ lossp,
                             const unsigned* __restrict__ cnt,
                             float* __restrict__ out_loss,
                             float* __restrict__ out_perp) {
    const int s   = blockIdx.x;
    const int tid = threadIdx.x;
    float ent = 0.f, lsum = 0.f;
    for (int i = tid; i < K; i += 256) {
        float p = (float)cnt[s * K + i] * (1.0f / 65536.0f);
        ent += p * logf(p + EPSQ);
    }
    for (int i = tid; i < NW; i += 256) lsum += lossp[s * NW + i];
    __shared__ float redE[4], redL[4];
#pragma unroll
    for (int off = 32; off > 0; off >>= 1) {
        ent  += __shfl_down(ent, off);
        lsum += __shfl_down(lsum, off);
    }
    if ((tid & 63) == 0) { redE[tid >> 6] = ent; redL[tid >> 6] = lsum; }
    __syncthreads();
    if (tid == 0) {
        float te = redE[0] + redE[1] + redE[2] + redE[3];
        float tl = redL[0] + redL[1] + redL[2] + redL[3];
        out_perp[s] = expf(-te);
        out_loss[s] = tl * (1.0f / NELEM);
    }
}

// ---------------------------------------------------------------------------
extern "C" void kernel_launch(void* const* d_in, const int* in_sizes, int n_in,
                              void* d_out, int out_size, void* d_ws, size_t ws_size,
                              hipStream_t stream) {
    const float* z  = (const float*)d_in[0];
    const float* cb = (const float*)d_in[1];

    float* zq       = (float*)d_out;
    float* out_loss = zq + 4194304;
    float* out_perp = out_loss + 8;

    // ws: cbi 2 MB | c2 32 KB | cnt 32 KB | lossp 128 KB
    char* ws = (char*)d_ws;
    unsigned short* cbi = (unsigned short*)(ws);
    float*    c2    = (float*)(ws + 2097152);
    unsigned* cnt   = (unsigned*)(ws + 2129920);
    float*    lossp = (float*)(ws + 2162688);

    hipLaunchKernelGGL(rvq_prep,     dim3(128),  dim3(256), 0, stream, cb, cbi, c2, cnt);
    hipLaunchKernelGGL(rvq_main,     dim3(NW),   dim3(64),  0, stream, z, cb, cbi, c2, zq, lossp, cnt);
    hipLaunchKernelGGL(rvq_finalize, dim3(S),    dim3(256), 0, stream, lossp, cnt, out_loss, out_perp);
}